// Round 9
// baseline (147.825 us; speedup 1.0000x reference)
//
#include <hip/hip_runtime.h>

// ---------------- problem constants ----------------
#define B_     32
#define C_     2
#define L_     160000
#define HOP    512
#define PAD    1024
#define LPAD   162048            // L_ + 2*PAD
#define T_     313               // frames
#define BC     64                // B_*C_
#define M_     20032             // BC*T_
#define KCH    1025              // output channels per (real|imag)
#define OUT_HALF 20532800UL      // M_*KCH
#define PL     81024             // plane length per bc (LPAD/2)
#define KD     1024              // decimated K
#define NKT    32                // KD/32 K-tiles
#define MTP    160               // M tiles padded to 8*20 (157 real)
#define NWG    1280              // MTP*8
#define LIMW   8336              // im word offset: 128*65+16

typedef __attribute__((ext_vector_type(8))) short short8;
typedef __attribute__((ext_vector_type(4))) float f32x4;

static __device__ __forceinline__ short f2bf(float f) {
  union { float f; unsigned u; } v; v.f = f;
  unsigned u = v.u;
  unsigned r = (u + 0x7fffu + ((u >> 16) & 1u)) >> 16;  // RNE
  return (short)r;
}

// ---------------- prep 1: even/odd deinterleaved reflect-padded planes ----------------
__global__ void prep_planes(const float* __restrict__ x,
                            short* __restrict__ pl0, short* __restrict__ pl1) {
  int v = blockIdx.x * 256 + threadIdx.x;           // < 64*10128 = 648192
  int bc = v / 10128;
  int r  = v - bc * 10128;
  int p0 = r * 8;                                   // 8 p-positions -> 16 samples
  const float* src = x + (size_t)bc * L_;
  short8 e, o;
  if (r >= 64 && r <= 10000) {                      // fully interior
    int j0 = 16 * r - 1024;
    #pragma unroll
    for (int qq = 0; qq < 4; ++qq) {
      float4 f = *(const float4*)(src + j0 + qq * 4);
      e[qq * 2 + 0] = f2bf(f.x); o[qq * 2 + 0] = f2bf(f.y);
      e[qq * 2 + 1] = f2bf(f.z); o[qq * 2 + 1] = f2bf(f.w);
    }
  } else {
    #pragma unroll
    for (int u = 0; u < 16; ++u) {
      int j = 16 * r + u - 1024;
      j = j < 0 ? -j : j;
      j = j >= L_ ? 2 * L_ - 2 - j : j;
      short b = f2bf(src[j]);
      if (u & 1) o[u >> 1] = b; else e[u >> 1] = b;
    }
  }
  *(short8*)&pl0[(size_t)bc * PL + p0] = e;
  *(short8*)&pl1[(size_t)bc * PL + p0] = o;
}

// ---------------- prep 2: windowed DFT-1024 weights, interleaved re/im rows ----------------
__global__ void prep_wb(short* __restrict__ wb0, short* __restrict__ wb1) {
  int id = blockIdx.x * 256 + threadIdx.x;          // < 2*1024*128 = 262144
  int s   = id >> 17;
  int row = (id >> 7) & 1023;
  int n8  = (id & 127) * 8;
  int kp  = row >> 1, e = row & 1;
  short8 ov;
  #pragma unroll
  for (int u = 0; u < 8; ++u) {
    int n1 = n8 + u;
    float win = 0.5f - 0.5f * cosf((float)(2 * n1 + s) * 3.0679615757712823e-3f); // pi/1024
    float tw;
    if (e == 0)       tw = cosf((float)((n1 * kp) & 1023) * 6.1359231515425649e-3f); // 2pi/1024
    else if (kp == 0) tw = (n1 & 1) ? -1.0f : 1.0f;       // cos(pi*n1): re[512] row
    else              tw = -sinf((float)((n1 * kp) & 1023) * 6.1359231515425649e-3f);
    ov[u] = f2bf(win * tw);
  }
  short* wb = s ? wb1 : wb0;
  *(short8*)&wb[(size_t)row * KD + n8] = ov;
}

// ---------------- GEMM: 128x128 tile, waves = 2m x 2n x 2s, BK=32 ----------------
#define GLOAD16(g, l) __builtin_amdgcn_global_load_lds(                        \
    (const __attribute__((address_space(1))) void*)(g),                        \
    (__attribute__((address_space(3))) void*)(l), 16, 0, 0)

__global__ __launch_bounds__(512, 4) void stft_gemm(const short* __restrict__ pl0,
                                                    const short* __restrict__ pl1,
                                                    const short* __restrict__ wb0,
                                                    const short* __restrict__ wb1,
                                                    float* __restrict__ out) {
  // main loop: 2 buffers x (A0,A1,B0,B1 each [128][32] = 8KB) = 64KB
  // epilogue reuse: lre[128][65] + pad + lim[128][65] fp32 = 66624 B
  __shared__ __align__(16) char lds[66688];
  const int tid  = threadIdx.x;
  const int lane = tid & 63;
  const int wid  = tid >> 6;          // 0..7

  // ---- XCD remap: 8 nt-blocks sharing an A-panel are consecutive ids with the
  // same id%8 -> same XCD -> A fetched ~once per panel; B (4MB) L2-resident.
  const int id = blockIdx.x;                   // 0..1279
  const int mt = (id & 7) * 20 + (id >> 6);    // 0..159 (>=157 dead-padded)
  const int nt = (id >> 3) & 7;
  const int M0 = mt * 128, N0 = nt * 128;

  // ---- wave roles: sw = plane, (wm, wn) = 64x64 sub-tile ----
  const int sw = wid & 1, wn = (wid >> 1) & 1, wm = wid >> 2;

  // ---- staging: 4 areas (A0,A1,B0,B1), 1 gload16 per thread per area ----
  const int srow  = tid >> 2;                                // 0..127
  const int chunk = ((tid & 3) ^ ((tid >> 3) & 3)) * 8;      // inverse-swizzled src
  const short *a0S, *a1S, *b0S, *b1S;
  {
    int m = M0 + srow; if (m > M_ - 1) m = M_ - 1;           // clamp (not stored)
    int bc = m / T_;
    int t  = m - bc * T_;
    size_t base = (size_t)bc * PL + (size_t)t * 256 + chunk;
    a0S = pl0 + base;
    a1S = pl1 + base;
    size_t bb = (size_t)(N0 + srow) * KD + chunk;
    b0S = wb0 + bb;
    b1S = wb1 + bb;
  }
  const int dst = tid * 16;   // linear LDS dest within each 8KB area

  // ---- fragment read offsets (proven conflict-free 64B-row XOR pattern) ----
  const int fr = lane & 15;
  const int xorb = ((lane >> 4) * 16) ^ ((fr & 6) << 3);
  int aOff[4], bOff[4];
  #pragma unroll
  for (int i = 0; i < 4; ++i)
    aOff[i] = sw * 8192 + (wm * 64 + i * 16 + fr) * 64 + xorb;
  #pragma unroll
  for (int j = 0; j < 4; ++j)
    bOff[j] = 16384 + sw * 8192 + (wn * 64 + j * 16 + fr) * 64 + xorb;

  f32x4 acc[4][4];
  #pragma unroll
  for (int i = 0; i < 4; ++i)
    #pragma unroll
    for (int j = 0; j < 4; ++j) acc[i][j] = (f32x4){0.f, 0.f, 0.f, 0.f};

  // ---- prologue: stage kt=0 into buffer 0 (4 loads in flight) ----
  GLOAD16(a0S, lds + dst);
  GLOAD16(a1S, lds + 8192 + dst);
  GLOAD16(b0S, lds + 16384 + dst);
  GLOAD16(b1S, lds + 24576 + dst);

  // ---- main loop: 2 barriers + counted vmcnt(4) per K-tile, 16 MFMA cluster ----
  // End-of-body barrier is the WAR guard: a wave reaches it only after its
  // MFMAs issued (=> its ds_reads drained), so next iteration's DMA writes
  // into bufR(kt) can't overwrite data any wave still needs. [round-8 racefix]
  for (int kt = 0; kt < NKT; ++kt) {
    char* bufR = lds + (kt & 1) * 32768;
    char* bufW = lds + ((kt + 1) & 1) * 32768;
    const int kos = (kt + 1) * 32;
    const bool st = (kt < NKT - 1);

    if (st) {  // issue next tile's 4 loads first -> vmcnt stays counted
      GLOAD16(a0S + kos, bufW + dst);
      GLOAD16(a1S + kos, bufW + 8192 + dst);
      GLOAD16(b0S + kos, bufW + 16384 + dst);
      GLOAD16(b1S + kos, bufW + 24576 + dst);
      asm volatile("s_waitcnt vmcnt(4)" ::: "memory");   // tile kt landed
    } else {
      asm volatile("s_waitcnt vmcnt(0)" ::: "memory");
    }
    __builtin_amdgcn_s_barrier();   // RAW: tile kt visible to all waves

    short8 af[4], bf[4];
    #pragma unroll
    for (int i = 0; i < 4; ++i) af[i] = *(const short8*)(bufR + aOff[i]);
    #pragma unroll
    for (int j = 0; j < 4; ++j) bf[j] = *(const short8*)(bufR + bOff[j]);
    __builtin_amdgcn_s_setprio(1);
    #pragma unroll
    for (int i = 0; i < 4; ++i)
      #pragma unroll
      for (int j = 0; j < 4; ++j)
        acc[i][j] = __builtin_amdgcn_mfma_f32_16x16x32_bf16(af[i], bf[j],
                                                            acc[i][j], 0, 0, 0);
    __builtin_amdgcn_s_setprio(0);
    __builtin_amdgcn_s_barrier();   // WAR: all reads of bufR consumed
  }

  // ---- epilogue: cross-wave twiddle combine via LDS, coalesced writes ----
  // X[q] = Y0[q] + t_q Y1[q];  s0 waves write base, s1 waves RMW the t-term.
  float* L = (float*)lds;
  float* outI = out + OUT_HALF;
  const float PIQ = 3.0679615757712823e-3f;     // pi/1024
  const int rgrp = (lane >> 4) << 2;

  __syncthreads();   // all main-loop LDS reads complete before reuse

  #pragma unroll
  for (int pass = 0; pass < 2; ++pass) {
    if (sw == 0) {     // base term: +/- Y0
      #pragma unroll
      for (int j = 0; j < 4; ++j) {
        int c  = wn * 64 + j * 16 + fr;         // local col 0..127
        int q  = c >> 1;
        bool odd  = c & 1;
        bool spec = (nt == 0) && (c == 1);      // Y[512] special slot
        int widx = (odd ? LIMW : 0) + (pass ? (63 - q) : q);
        #pragma unroll
        for (int i = 0; i < 4; ++i) {
          int row = wm * 64 + i * 16 + rgrp;
          #pragma unroll
          for (int r = 0; r < 4; ++r) {
            float v0 = acc[i][j][r];
            float base = pass == 0 ? v0 : (odd ? -v0 : v0);
            if (spec) base = 0.f;
            L[widx + (row + r) * 65] = base;
            if (spec && pass == 0) {
              int gm = M0 + row + r;
              if (gm < M_) out[(size_t)gm * KCH + 512] = v0;   // X[512].re = Y0[512]
            }
          }
        }
      }
    }
    __syncthreads();
    if (sw == 1) {     // twiddle term: +/- t_q * Y1
      #pragma unroll
      for (int j = 0; j < 4; ++j) {
        int c  = wn * 64 + j * 16 + fr;
        int q  = c >> 1;
        float ang = (float)(nt * 64 + q) * PIQ;
        float tr = cosf(ang), sn = sinf(ang);
        bool odd  = c & 1;
        bool spec = (nt == 0) && (c == 1);
        float sgn = odd ? -sn : sn;
        int widx = (odd ? LIMW : 0) + (pass ? (63 - q) : q);
        #pragma unroll
        for (int i = 0; i < 4; ++i) {
          int row = wm * 64 + i * 16 + rgrp;
          #pragma unroll
          for (int r = 0; r < 4; ++r) {
            float v1 = acc[i][j][r];
            float p1 = __shfl_xor(v1, 1);
            float u  = tr * v1 + sgn * p1;
            if (!spec) {
              float addv = (pass == 0) ? u : (odd ? u : -u);
              int li = widx + (row + r) * 65;
              L[li] += addv;
            } else if (pass == 0) {
              int gm = M0 + row + r;
              if (gm < M_) outI[(size_t)gm * KCH + 512] = -v1; // X[512].im = -Y1[512]
            }
          }
        }
      }
    }
    __syncthreads();
    // coalesced write: each wave writes whole rows (64 consecutive floats)
    {
      int col0 = pass ? (1024 - nt * 64 - 63) : (nt * 64);
      #pragma unroll
      for (int i2 = 0; i2 < 16; ++i2) {
        int row = wid + i2 * 8;
        int gm  = M0 + row;
        if (gm < M_) {
          size_t rb = (size_t)gm * KCH + col0 + lane;
          out [rb] = L[row * 65 + lane];
          outI[rb] = L[LIMW + row * 65 + lane];
        }
      }
    }
    __syncthreads();   // arrays reused by next pass
  }
}

// ---------------- launcher ----------------
extern "C" void kernel_launch(void* const* d_in, const int* in_sizes, int n_in,
                              void* d_out, int out_size, void* d_ws, size_t ws_size,
                              hipStream_t stream) {
  const float* x = (const float*)d_in[0];
  float* out = (float*)d_out;

  short* pl0 = (short*)d_ws;                        // 64*81024 bf16
  short* pl1 = pl0 + (size_t)BC * PL;
  short* wb0 = pl1 + (size_t)BC * PL;               // 1024*1024
  short* wb1 = wb0 + (size_t)1024 * KD;             // total 24.9 MB

  prep_planes<<<2532, 256, 0, stream>>>(x, pl0, pl1);
  prep_wb<<<1024, 256, 0, stream>>>(wb0, wb1);

  stft_gemm<<<NWG, 512, 0, stream>>>(pl0, pl1, wb0, wb1, out);
}